// Round 4
// baseline (84.519 us; speedup 1.0000x reference)
//
#include <hip/hip_runtime.h>
#include <hip/hip_bf16.h>

#define BB 8
#define NN 1024
#define FIN 512
#define HH 8
#define FOUT 64
#define HF 512
#define SLOPE 0.2f
#define ECAP 64

typedef __attribute__((ext_vector_type(8))) short bf16x8;
typedef __attribute__((ext_vector_type(4))) float f32x4;
typedef unsigned long long ull;

static __device__ __forceinline__ float lrelu(float v) { return v > 0.0f ? v : SLOPE * v; }

static __device__ __forceinline__ unsigned short f2bf(float f) {
  __hip_bfloat16 h = __float2bfloat16(f);
  return *reinterpret_cast<unsigned short*>(&h);
}
static __device__ __forceinline__ float bflo(unsigned v) {
  unsigned u = v << 16;
  return *reinterpret_cast<float*>(&u);
}
static __device__ __forceinline__ float bfhi(unsigned v) {
  unsigned u = v & 0xffff0000u;
  return *reinterpret_cast<float*>(&u);
}

// ---------------------------------------------------------------------------
// adjacency dtype detect via guaranteed self-loop diagonal
// mode 1 = int32, mode 2 = float32, mode 0 = 1-byte bool
// ---------------------------------------------------------------------------
static __device__ __forceinline__ void detect_adj(const void* adj, int* flag) {
  const int* ai = (const int*)adj;
  const float* af = (const float*)adj;
  bool oki = true, okf = true;
  for (int i = 0; i < 64; ++i) {
    int d = i * (NN + 1);
    oki = oki && (ai[d] == 1);
    okf = okf && (af[d] == 1.0f);
  }
  *flag = oki ? 1 : (okf ? 2 : 0);
}

// ---------------------------------------------------------------------------
// W transpose+cast body: W (FIN x HF, f32) -> Wt (HF x FIN, bf16)
// ---------------------------------------------------------------------------
static __device__ __forceinline__ void prep_body(const float* W,
                                                 unsigned short* Wt, int bx,
                                                 int by, int t) {
  __shared__ float tile[64][65];
  const int r0 = by * 64, c0 = bx * 64;
#pragma unroll
  for (int p = 0; p < 16; ++p) {
    int r = (t >> 6) + p * 4;
    tile[t & 63][r] = W[(size_t)(r0 + r) * HF + c0 + (t & 63)];
  }
  __syncthreads();
#pragma unroll
  for (int p = 0; p < 16; ++p) {
    int cc = (t >> 6) + p * 4;
    int rr = t & 63;
    Wt[(size_t)(c0 + cc) * FIN + r0 + rr] = f2bf(tile[cc][rr]);
  }
}

// fallback-path prep (identical to R3)
__global__ __launch_bounds__(256) void k_prep(const float* __restrict__ W,
                                              unsigned short* __restrict__ Wt,
                                              const void* __restrict__ adj,
                                              int* __restrict__ flag) {
  if (blockIdx.x == 0 && blockIdx.y == 0 && threadIdx.x == 0)
    detect_adj(adj, flag);
  prep_body(W, Wt, blockIdx.x, blockIdx.y, threadIdx.x);
}

// ---------------------------------------------------------------------------
// fast-path K1: cast x (f32) -> xb (bf16, row-major); blocks 0..63 also do
// the W transpose; block 0 thread 0 detects adjacency dtype.
// ---------------------------------------------------------------------------
__global__ __launch_bounds__(256) void k_cast(const float* __restrict__ x,
                                              unsigned short* __restrict__ xb,
                                              const float* __restrict__ W,
                                              unsigned short* __restrict__ Wt,
                                              const void* __restrict__ adj,
                                              int* __restrict__ flag) {
  const int bid = blockIdx.x;
  const int t = threadIdx.x;
  if (bid == 0 && t == 0) detect_adj(adj, flag);
  // cast: thread -> 8 consecutive elements
  const size_t e0 = ((size_t)bid * 256 + t) * 8;
  float4 v0 = *(const float4*)(x + e0);
  float4 v1 = *(const float4*)(x + e0 + 4);
  ushort4 o0, o1;
  o0.x = f2bf(v0.x); o0.y = f2bf(v0.y); o0.z = f2bf(v0.z); o0.w = f2bf(v0.w);
  o1.x = f2bf(v1.x); o1.y = f2bf(v1.y); o1.z = f2bf(v1.z); o1.w = f2bf(v1.w);
  *(ushort4*)(xb + e0) = o0;
  *(ushort4*)(xb + e0 + 4) = o1;
  if (bid < 64) prep_body(W, Wt, bid & 7, bid >> 3, t);
}

// ---------------------------------------------------------------------------
// fast-path K2: LDS-free MFMA GEMM. Wh = xb @ Wt^T.
// 64x64 tile, 4 waves (2x2), wave = 32x32 via 2x2 frags of 16x16x32.
// A/B fragments loaded straight from global (L2-resident).
// Fused e_src/e_dst epilogue.
// ---------------------------------------------------------------------------
__global__ __launch_bounds__(256) void k_gemm_f(
    const unsigned short* __restrict__ xb, const unsigned short* __restrict__ Wt,
    const float* __restrict__ a, unsigned short* __restrict__ Wh,
    float* __restrict__ e_src, float* __restrict__ e_dst) {
  __shared__ float eps[2][64], epd[2][64];

  const int t = threadIdx.x;
  const int wave = t >> 6, lane = t & 63;
  const int wr = wave >> 1, wc = wave & 1;
  const int row0 = blockIdx.x * 64, col0 = blockIdx.y * 64;
  const int bn = blockIdx.y;  // head

  const int rA = row0 + wr * 32 + (lane & 15);
  const int cB = col0 + wc * 32 + (lane & 15);
  const unsigned short* pa0 = xb + (size_t)rA * FIN;
  const unsigned short* pa1 = pa0 + 16 * FIN;
  const unsigned short* pb0 = Wt + (size_t)cB * FIN;
  const unsigned short* pb1 = pb0 + 16 * FIN;
  const int kc0 = (lane >> 4) * 8;

  f32x4 acc[2][2] = {};
#pragma unroll
  for (int ks = 0; ks < 16; ++ks) {  // K = 512 = 16 substeps of 32
    const int ko = ks * 32 + kc0;
    bf16x8 a0 = *(const bf16x8*)(pa0 + ko);
    bf16x8 a1 = *(const bf16x8*)(pa1 + ko);
    bf16x8 b0 = *(const bf16x8*)(pb0 + ko);
    bf16x8 b1 = *(const bf16x8*)(pb1 + ko);
    acc[0][0] = __builtin_amdgcn_mfma_f32_16x16x32_bf16(a0, b0, acc[0][0], 0, 0, 0);
    acc[0][1] = __builtin_amdgcn_mfma_f32_16x16x32_bf16(a0, b1, acc[0][1], 0, 0, 0);
    acc[1][0] = __builtin_amdgcn_mfma_f32_16x16x32_bf16(a1, b0, acc[1][0], 0, 0, 0);
    acc[1][1] = __builtin_amdgcn_mfma_f32_16x16x32_bf16(a1, b1, acc[1][1], 0, 0, 0);
  }

  // Wh store (C/D: col=lane&15, row=(lane>>4)*4+r)
#pragma unroll
  for (int m = 0; m < 2; ++m)
#pragma unroll
    for (int n = 0; n < 2; ++n)
#pragma unroll
      for (int r = 0; r < 4; ++r) {
        const int row = row0 + wr * 32 + m * 16 + (lane >> 4) * 4 + r;
        const int col = col0 + wc * 32 + n * 16 + (lane & 15);
        Wh[(size_t)row * HF + col] = f2bf(acc[m][n][r]);
      }

  // fused e_src/e_dst epilogue
  float av_s[2], av_d[2];
#pragma unroll
  for (int n = 0; n < 2; ++n) {
    const int cl = wc * 32 + n * 16 + (lane & 15);
    av_s[n] = a[bn * 2 * FOUT + cl];
    av_d[n] = a[bn * 2 * FOUT + FOUT + cl];
  }
#pragma unroll
  for (int m = 0; m < 2; ++m)
#pragma unroll
    for (int r = 0; r < 4; ++r) {
      float ps = acc[m][0][r] * av_s[0] + acc[m][1][r] * av_s[1];
      float pd = acc[m][0][r] * av_d[0] + acc[m][1][r] * av_d[1];
#pragma unroll
      for (int s = 1; s < 16; s <<= 1) {
        ps += __shfl_xor(ps, s);
        pd += __shfl_xor(pd, s);
      }
      if ((lane & 15) == 0) {
        const int rl = wr * 32 + m * 16 + (lane >> 4) * 4 + r;
        eps[wc][rl] = ps;
        epd[wc][rl] = pd;
      }
    }
  __syncthreads();
  if (t < 64) {
    e_src[(size_t)(row0 + t) * HH + bn] = eps[0][t] + eps[1][t];
    e_dst[(size_t)(row0 + t) * HH + bn] = epd[0][t] + epd[1][t];
  }
}

// ---------------------------------------------------------------------------
// fallback K2 (R3's LDS-staged GEMM, unchanged)
// ---------------------------------------------------------------------------
__global__ __launch_bounds__(256) void k_gemm(const float* __restrict__ x,
                                              const unsigned short* __restrict__ Wt,
                                              const float* __restrict__ a,
                                              unsigned short* __restrict__ Wh,
                                              float* __restrict__ e_src,
                                              float* __restrict__ e_dst) {
  __shared__ short As[64 * 64];
  __shared__ short Bs[64 * 64];
  __shared__ float eps[2][64], epd[2][64];

  const int t = threadIdx.x;
  const int wave = t >> 6, lane = t & 63;
  const int wr = wave >> 1, wc = wave & 1;
  const int row0 = blockIdx.x * 64, col0 = blockIdx.y * 64;
  const int bn = blockIdx.y;

  f32x4 acc[2][2] = {};
  const int sr = t >> 3;
  const int skc = t & 7;

  for (int k0 = 0; k0 < FIN; k0 += 64) {
    __syncthreads();
#pragma unroll
    for (int ss = 0; ss < 2; ++ss) {
      const int row = sr + ss * 32;
      const int ksrc = k0 + ((skc ^ (row & 7)) << 3);
      const float4* g = (const float4*)(x + (size_t)(row0 + row) * FIN + ksrc);
      float4 v0 = g[0], v1 = g[1];
      bf16x8 pk;
      unsigned short* u = (unsigned short*)&pk;
      u[0] = f2bf(v0.x); u[1] = f2bf(v0.y); u[2] = f2bf(v0.z); u[3] = f2bf(v0.w);
      u[4] = f2bf(v1.x); u[5] = f2bf(v1.y); u[6] = f2bf(v1.z); u[7] = f2bf(v1.w);
      *(bf16x8*)(&As[row * 64 + skc * 8]) = pk;
      uint4 wv = *(const uint4*)(Wt + (size_t)(col0 + row) * FIN + ksrc);
      *(uint4*)(&Bs[row * 64 + skc * 8]) = wv;
    }
    __syncthreads();
#pragma unroll
    for (int s = 0; s < 2; ++s) {
      const int kc = s * 4 + (lane >> 4);
      bf16x8 af[2], bfr[2];
#pragma unroll
      for (int m = 0; m < 2; ++m) {
        const int row = wr * 32 + m * 16 + (lane & 15);
        af[m] = *(const bf16x8*)(&As[row * 64 + (kc ^ (row & 7)) * 8]);
      }
#pragma unroll
      for (int n = 0; n < 2; ++n) {
        const int col = wc * 32 + n * 16 + (lane & 15);
        bfr[n] = *(const bf16x8*)(&Bs[col * 64 + (kc ^ (col & 7)) * 8]);
      }
#pragma unroll
      for (int m = 0; m < 2; ++m)
#pragma unroll
        for (int n = 0; n < 2; ++n)
          acc[m][n] = __builtin_amdgcn_mfma_f32_16x16x32_bf16(af[m], bfr[n], acc[m][n], 0, 0, 0);
    }
  }
#pragma unroll
  for (int m = 0; m < 2; ++m)
#pragma unroll
    for (int n = 0; n < 2; ++n)
#pragma unroll
      for (int r = 0; r < 4; ++r) {
        const int row = row0 + wr * 32 + m * 16 + (lane >> 4) * 4 + r;
        const int col = col0 + wc * 32 + n * 16 + (lane & 15);
        Wh[(size_t)row * HF + col] = f2bf(acc[m][n][r]);
      }
  float av_s[2], av_d[2];
#pragma unroll
  for (int n = 0; n < 2; ++n) {
    const int cl = wc * 32 + n * 16 + (lane & 15);
    av_s[n] = a[bn * 2 * FOUT + cl];
    av_d[n] = a[bn * 2 * FOUT + FOUT + cl];
  }
#pragma unroll
  for (int m = 0; m < 2; ++m)
#pragma unroll
    for (int r = 0; r < 4; ++r) {
      float ps = acc[m][0][r] * av_s[0] + acc[m][1][r] * av_s[1];
      float pd = acc[m][0][r] * av_d[0] + acc[m][1][r] * av_d[1];
#pragma unroll
      for (int s = 1; s < 16; s <<= 1) {
        ps += __shfl_xor(ps, s);
        pd += __shfl_xor(pd, s);
      }
      if ((lane & 15) == 0) {
        const int rl = wr * 32 + m * 16 + (lane >> 4) * 4 + r;
        eps[wc][rl] = ps;
        epd[wc][rl] = pd;
      }
    }
  __syncthreads();
  if (t < 64) {
    e_src[(size_t)(row0 + t) * HH + bn] = eps[0][t] + eps[1][t];
    e_dst[(size_t)(row0 + t) * HH + bn] = epd[0][t] + epd[1][t];
  }
}

// ---------------------------------------------------------------------------
// K3: fused sparse attention + skip + LayerNorm.
// One WAVE per (b,i) row, 4 rows/block, zero barriers, XCD-swizzled blocks.
// ---------------------------------------------------------------------------
__global__ __launch_bounds__(256) void k_attn(
    const float* __restrict__ x, const void* __restrict__ adj,
    const int* __restrict__ flag, const unsigned short* __restrict__ Wh,
    const float* __restrict__ e_src, const float* __restrict__ e_dst,
    const float* __restrict__ gamma, const float* __restrict__ beta,
    float* __restrict__ out) {
  __shared__ unsigned short nbrs[4][NN];
  __shared__ float edbuf[4][ECAP * 8];
  __shared__ float esb[4][8], erm[4][8], einv[4][8];

  const int wave = threadIdx.x >> 6, lane = threadIdx.x & 63;
  // XCD swizzle: 2048 blocks, 8 XCDs -> XCD x owns batch x (L2-resident slice)
  const int bid = blockIdx.x;
  const int nbid = (bid & 7) * 256 + (bid >> 3);
  const int gr = nbid * 4 + wave;        // global row = b*NN + i
  const int bN = (gr >> 10) << 10;       // b*NN
  const size_t arow = (size_t)gr << 10;
  const int mode = *flag;

  unsigned short* nb = nbrs[wave];
  float* ed = edbuf[wave];

  // ---- phase 1: in-wave neighbor compaction (4 rounds x 4 ballots) ----
  int off = 0;
#pragma unroll
  for (int rr = 0; rr < 4; ++rr) {
    const int j0 = rr * 256 + lane * 4;
    bool v0, v1, v2, v3;
    if (mode == 1) {
      int4 q = *((const int4*)((const int*)adj + arow + j0));
      v0 = q.x != 0; v1 = q.y != 0; v2 = q.z != 0; v3 = q.w != 0;
    } else if (mode == 2) {
      float4 q = *((const float4*)((const float*)adj + arow + j0));
      v0 = q.x != 0.f; v1 = q.y != 0.f; v2 = q.z != 0.f; v3 = q.w != 0.f;
    } else {
      unsigned q = *((const unsigned*)((const unsigned char*)adj + arow + j0));
      v0 = (q & 0xffu) != 0; v1 = (q & 0xff00u) != 0;
      v2 = (q & 0xff0000u) != 0; v3 = (q >> 24) != 0;
    }
    ull m0 = __ballot(v0), m1 = __ballot(v1);
    ull m2 = __ballot(v2), m3 = __ballot(v3);
    const ull below = (1ull << lane) - 1ull;
    int base = off + __popcll(m0 & below) + __popcll(m1 & below) +
               __popcll(m2 & below) + __popcll(m3 & below);
    int c = 0;
    if (v0) nb[base + c++] = (unsigned short)(j0 + 0);
    if (v1) nb[base + c++] = (unsigned short)(j0 + 1);
    if (v2) nb[base + c++] = (unsigned short)(j0 + 2);
    if (v3) nb[base + c++] = (unsigned short)(j0 + 3);
    off += __popcll(m0) + __popcll(m1) + __popcll(m2) + __popcll(m3);
  }
  const int total = off;
  const int ncap = total < ECAP ? total : ECAP;

  // ---- phase 2: gather e_dst (lane=(kq,h)), softmax stats for 8 heads ----
  const int h = lane & 7, kq = lane >> 3;
  for (int k = kq; k < ncap; k += 8)
    ed[k * 8 + h] = e_dst[(size_t)(bN + nb[k]) * HH + h];

  const float es = e_src[(size_t)gr * HH + h];
  float mx = -1e30f;
  for (int k = kq; k < total; k += 8) {
    float v = (k < ECAP) ? ed[k * 8 + h] : e_dst[(size_t)(bN + nb[k]) * HH + h];
    mx = fmaxf(mx, v);
  }
  mx = fmaxf(mx, __shfl_xor(mx, 8));
  mx = fmaxf(mx, __shfl_xor(mx, 16));
  mx = fmaxf(mx, __shfl_xor(mx, 32));
  const float rm = lrelu(es + mx);

  float z = 0.0f;
  for (int k = kq; k < total; k += 8) {
    float v = (k < ECAP) ? ed[k * 8 + h] : e_dst[(size_t)(bN + nb[k]) * HH + h];
    float w = __expf(lrelu(es + v) - rm);
    if (k < ECAP) ed[k * 8 + h] = w;  // unscaled weight
    z += w;
  }
  z += __shfl_xor(z, 8);
  z += __shfl_xor(z, 16);
  z += __shfl_xor(z, 32);
  if (kq == 0) {
    esb[wave][h] = es;
    erm[wave][h] = rm;
    einv[wave][h] = 1.0f / z;
  }

  // ---- phase 3: weighted accumulation, 4-deep pipelined gather ----
  const int h2 = lane >> 3;
  const float es2 = esb[wave][h2], rm2 = erm[wave][h2];
  const int feat = lane * 8;
  const unsigned short* whB = Wh + (size_t)bN * HF + feat;
  float aA0 = 0, aA1 = 0, aA2 = 0, aA3 = 0, aA4 = 0, aA5 = 0, aA6 = 0, aA7 = 0;
  float aB0 = 0, aB1 = 0, aB2 = 0, aB3 = 0, aB4 = 0, aB5 = 0, aB6 = 0, aB7 = 0;
  int k = 0;
  for (; k + 4 <= ncap; k += 4) {
    const unsigned j0 = nb[k + 0], j1 = nb[k + 1];
    const unsigned j2 = nb[k + 2], j3 = nb[k + 3];
    const float w0 = ed[(k + 0) * 8 + h2];
    const float w1 = ed[(k + 1) * 8 + h2];
    const float w2 = ed[(k + 2) * 8 + h2];
    const float w3 = ed[(k + 3) * 8 + h2];
    uint4 q0 = *(const uint4*)(whB + (size_t)j0 * HF);
    uint4 q1 = *(const uint4*)(whB + (size_t)j1 * HF);
    uint4 q2 = *(const uint4*)(whB + (size_t)j2 * HF);
    uint4 q3 = *(const uint4*)(whB + (size_t)j3 * HF);
    aA0 += w0 * bflo(q0.x); aA1 += w0 * bfhi(q0.x);
    aA2 += w0 * bflo(q0.y); aA3 += w0 * bfhi(q0.y);
    aA4 += w0 * bflo(q0.z); aA5 += w0 * bfhi(q0.z);
    aA6 += w0 * bflo(q0.w); aA7 += w0 * bfhi(q0.w);
    aB0 += w1 * bflo(q1.x); aB1 += w1 * bfhi(q1.x);
    aB2 += w1 * bflo(q1.y); aB3 += w1 * bfhi(q1.y);
    aB4 += w1 * bflo(q1.z); aB5 += w1 * bfhi(q1.z);
    aB6 += w1 * bflo(q1.w); aB7 += w1 * bfhi(q1.w);
    aA0 += w2 * bflo(q2.x); aA1 += w2 * bfhi(q2.x);
    aA2 += w2 * bflo(q2.y); aA3 += w2 * bfhi(q2.y);
    aA4 += w2 * bflo(q2.z); aA5 += w2 * bfhi(q2.z);
    aA6 += w2 * bflo(q2.w); aA7 += w2 * bfhi(q2.w);
    aB0 += w3 * bflo(q3.x); aB1 += w3 * bfhi(q3.x);
    aB2 += w3 * bflo(q3.y); aB3 += w3 * bfhi(q3.y);
    aB4 += w3 * bflo(q3.z); aB5 += w3 * bfhi(q3.z);
    aB6 += w3 * bflo(q3.w); aB7 += w3 * bfhi(q3.w);
  }
  for (; k < ncap; ++k) {
    const unsigned j = nb[k];
    const float w = ed[k * 8 + h2];
    uint4 q = *(const uint4*)(whB + (size_t)j * HF);
    aA0 += w * bflo(q.x); aA1 += w * bfhi(q.x);
    aA2 += w * bflo(q.y); aA3 += w * bfhi(q.y);
    aA4 += w * bflo(q.z); aA5 += w * bfhi(q.z);
    aA6 += w * bflo(q.w); aA7 += w * bfhi(q.w);
  }
  for (; k < total; ++k) {  // rare tail beyond ECAP (exact)
    const unsigned j = nb[k];
    const float w = __expf(lrelu(es2 + e_dst[(size_t)(bN + j) * HH + h2]) - rm2);
    uint4 q = *(const uint4*)(whB + (size_t)j * HF);
    aA0 += w * bflo(q.x); aA1 += w * bfhi(q.x);
    aA2 += w * bflo(q.y); aA3 += w * bfhi(q.y);
    aA4 += w * bflo(q.z); aA5 += w * bfhi(q.z);
    aA6 += w * bflo(q.w); aA7 += w * bfhi(q.w);
  }
  const float inv = einv[wave][h2];

  // ---- phase 4: skip + LayerNorm (512 feats across the wave) ----
  const size_t xo = (size_t)gr * HF + feat;
  float4 xv0 = *(const float4*)(x + xo);
  float4 xv1 = *(const float4*)(x + xo + 4);
  float v0 = (aA0 + aB0) * inv + xv0.x, v1 = (aA1 + aB1) * inv + xv0.y;
  float v2 = (aA2 + aB2) * inv + xv0.z, v3 = (aA3 + aB3) * inv + xv0.w;
  float v4 = (aA4 + aB4) * inv + xv1.x, v5 = (aA5 + aB5) * inv + xv1.y;
  float v6 = (aA6 + aB6) * inv + xv1.z, v7 = (aA7 + aB7) * inv + xv1.w;

  float s = v0 + v1 + v2 + v3 + v4 + v5 + v6 + v7;
  float ss = v0 * v0 + v1 * v1 + v2 * v2 + v3 * v3 +
             v4 * v4 + v5 * v5 + v6 * v6 + v7 * v7;
#pragma unroll
  for (int sft = 1; sft < 64; sft <<= 1) {
    s += __shfl_xor(s, sft);
    ss += __shfl_xor(ss, sft);
  }
  const float mu = s * (1.0f / 512.0f);
  const float var = ss * (1.0f / 512.0f) - mu * mu;
  const float rstd = rsqrtf(var + 1e-5f);

  float4 g0 = *(const float4*)(gamma + feat);
  float4 g1 = *(const float4*)(gamma + feat + 4);
  float4 b0 = *(const float4*)(beta + feat);
  float4 b1 = *(const float4*)(beta + feat + 4);
  float4 o0, o1;
  o0.x = (v0 - mu) * rstd * g0.x + b0.x;
  o0.y = (v1 - mu) * rstd * g0.y + b0.y;
  o0.z = (v2 - mu) * rstd * g0.z + b0.z;
  o0.w = (v3 - mu) * rstd * g0.w + b0.w;
  o1.x = (v4 - mu) * rstd * g1.x + b1.x;
  o1.y = (v5 - mu) * rstd * g1.y + b1.y;
  o1.z = (v6 - mu) * rstd * g1.z + b1.z;
  o1.w = (v7 - mu) * rstd * g1.w + b1.w;
  *(float4*)(out + xo) = o0;
  *(float4*)(out + xo + 4) = o1;
}

extern "C" void kernel_launch(void* const* d_in, const int* in_sizes, int n_in,
                              void* d_out, int out_size, void* d_ws,
                              size_t ws_size, hipStream_t stream) {
  const float* x = (const float*)d_in[0];
  const void* adj = d_in[1];
  const float* W = (const float*)d_in[2];
  const float* a = (const float*)d_in[3];
  const float* gamma = (const float*)d_in[4];
  const float* beta = (const float*)d_in[5];
  float* out = (float*)d_out;

  char* ws = (char*)d_ws;
  int* flag = (int*)ws;
  unsigned short* Wh = (unsigned short*)(ws + 256);                  // 8 MB
  unsigned short* Wt = (unsigned short*)(ws + 256 + 8388608);        // 512 KB
  float* e_src = (float*)(ws + 256 + 8388608 + 524288);              // 256 KB
  float* e_dst = e_src + (size_t)BB * NN * HH;                       // 256 KB
  unsigned short* xb = (unsigned short*)(ws + 256 + 8388608 + 524288 + 524288);  // 8 MB
  const size_t need = 256 + 8388608 + 524288 + 524288 + 8388608;

  if (ws_size >= need) {
    k_cast<<<2048, 256, 0, stream>>>(x, xb, W, Wt, adj, flag);
    k_gemm_f<<<dim3(128, 8), 256, 0, stream>>>(xb, Wt, a, Wh, e_src, e_dst);
  } else {
    k_prep<<<dim3(8, 8), 256, 0, stream>>>(W, Wt, adj, flag);
    k_gemm<<<dim3(128, 8), 256, 0, stream>>>(x, Wt, a, Wh, e_src, e_dst);
  }
  k_attn<<<2048, 256, 0, stream>>>(x, adj, flag, Wh, e_src, e_dst, gamma,
                                   beta, out);
}

// Round 5
// 75.392 us; speedup vs baseline: 1.1211x; 1.1211x over previous
//
#include <hip/hip_runtime.h>
#include <hip/hip_bf16.h>

#define BB 8
#define NN 1024
#define FIN 512
#define HH 8
#define FOUT 64
#define HF 512
#define SLOPE 0.2f
#define ECAP 64

typedef __attribute__((ext_vector_type(8))) short bf16x8;
typedef __attribute__((ext_vector_type(4))) float f32x4;
typedef unsigned long long ull;

static __device__ __forceinline__ float lrelu(float v) { return v > 0.0f ? v : SLOPE * v; }

static __device__ __forceinline__ unsigned short f2bf(float f) {
  __hip_bfloat16 h = __float2bfloat16(f);
  return *reinterpret_cast<unsigned short*>(&h);
}
static __device__ __forceinline__ float bflo(unsigned v) {
  unsigned u = v << 16;
  return *reinterpret_cast<float*>(&u);
}
static __device__ __forceinline__ float bfhi(unsigned v) {
  unsigned u = v & 0xffff0000u;
  return *reinterpret_cast<float*>(&u);
}

// ---------------------------------------------------------------------------
// adjacency dtype detect via guaranteed self-loop diagonal
// mode 1 = int32, mode 2 = float32, mode 0 = 1-byte bool
// ---------------------------------------------------------------------------
static __device__ __forceinline__ void detect_adj(const void* adj, int* flag) {
  const int* ai = (const int*)adj;
  const float* af = (const float*)adj;
  bool oki = true, okf = true;
  for (int i = 0; i < 64; ++i) {
    int d = i * (NN + 1);
    oki = oki && (ai[d] == 1);
    okf = okf && (af[d] == 1.0f);
  }
  *flag = oki ? 1 : (okf ? 2 : 0);
}

// ---------------------------------------------------------------------------
// K1: W transpose+cast: W (FIN x HF, f32) -> Wt (HF x FIN, bf16).
// Block 0 thread 0 also detects adjacency dtype.
// ---------------------------------------------------------------------------
__global__ __launch_bounds__(256) void k_prep(const float* __restrict__ W,
                                              unsigned short* __restrict__ Wt,
                                              const void* __restrict__ adj,
                                              int* __restrict__ flag) {
  if (blockIdx.x == 0 && blockIdx.y == 0 && threadIdx.x == 0)
    detect_adj(adj, flag);
  __shared__ float tile[64][65];
  const int t = threadIdx.x;
  const int r0 = blockIdx.y * 64, c0 = blockIdx.x * 64;
#pragma unroll
  for (int p = 0; p < 16; ++p) {
    int r = (t >> 6) + p * 4;
    tile[t & 63][r] = W[(size_t)(r0 + r) * HF + c0 + (t & 63)];
  }
  __syncthreads();
#pragma unroll
  for (int p = 0; p < 16; ++p) {
    int cc = (t >> 6) + p * 4;
    int rr = t & 63;
    Wt[(size_t)(c0 + cc) * FIN + r0 + rr] = f2bf(tile[cc][rr]);
  }
}

// ---------------------------------------------------------------------------
// K2: Wh = x @ W via bf16 MFMA. One block = 32 rows x ALL 512 cols.
// 512 threads = 8 waves; wave w computes head w (32x64) as 2x4 frags of
// 16x16x32. x staged once per row-tile into LDS (f32->bf16, XOR-swizzled);
// B fragments straight from global (L2-resident 0.5 MB Wt).
// Fused e_src/e_dst epilogue (wave-local, no LDS combine).
// ---------------------------------------------------------------------------
__global__ __launch_bounds__(512) void k_gemm2(
    const float* __restrict__ x, const unsigned short* __restrict__ Wt,
    const float* __restrict__ a, unsigned short* __restrict__ Wh,
    float* __restrict__ e_src, float* __restrict__ e_dst) {
  __shared__ short As[32 * 128];  // 8 KB: [row][128 k] bf16, chunk-swizzled

  const int t = threadIdx.x;
  const int wave = t >> 6, lane = t & 63;  // wave == head
  const int row0 = blockIdx.x * 32;
  const int col0 = wave * 64;

  const int lr = lane & 15;  // row/col within fragment
  const int kq = lane >> 4;  // k-quad 0..3

  // staging: thread t stages row = t>>4, 8-bf16 chunk = t&15
  const int srow = t >> 4;
  const int schunk = t & 15;

  f32x4 acc[2][4] = {};

  for (int k0 = 0; k0 < FIN; k0 += 128) {
    __syncthreads();
    {
      const int csrc = schunk ^ (srow & 7);  // pre-swizzled source chunk
      const float4* g =
          (const float4*)(x + (size_t)(row0 + srow) * FIN + k0 + csrc * 8);
      float4 v0 = g[0], v1 = g[1];
      bf16x8 pk;
      unsigned short* u = (unsigned short*)&pk;
      u[0] = f2bf(v0.x); u[1] = f2bf(v0.y); u[2] = f2bf(v0.z); u[3] = f2bf(v0.w);
      u[4] = f2bf(v1.x); u[5] = f2bf(v1.y); u[6] = f2bf(v1.z); u[7] = f2bf(v1.w);
      *(bf16x8*)(&As[srow * 128 + schunk * 8]) = pk;
    }
    __syncthreads();
#pragma unroll
    for (int ks = 0; ks < 4; ++ks) {
      bf16x8 af[2];
#pragma unroll
      for (int m = 0; m < 2; ++m) {
        const int row = m * 16 + lr;
        const int chunk = (ks * 4 + kq) ^ (row & 7);
        af[m] = *(const bf16x8*)(&As[row * 128 + chunk * 8]);
      }
#pragma unroll
      for (int n = 0; n < 4; ++n) {
        const int col = col0 + n * 16 + lr;
        bf16x8 bfr = *(const bf16x8*)(Wt + (size_t)col * FIN + k0 + ks * 32 + kq * 8);
        acc[0][n] = __builtin_amdgcn_mfma_f32_16x16x32_bf16(af[0], bfr, acc[0][n], 0, 0, 0);
        acc[1][n] = __builtin_amdgcn_mfma_f32_16x16x32_bf16(af[1], bfr, acc[1][n], 0, 0, 0);
      }
    }
  }

  // Wh store (C/D: col=lane&15, row=kq*4+r within frag)
#pragma unroll
  for (int m = 0; m < 2; ++m)
#pragma unroll
    for (int n = 0; n < 4; ++n)
#pragma unroll
      for (int r = 0; r < 4; ++r) {
        const int row = row0 + m * 16 + kq * 4 + r;
        const int col = col0 + n * 16 + lr;
        Wh[(size_t)row * HF + col] = f2bf(acc[m][n][r]);
      }

  // fused e_src/e_dst epilogue (wave owns whole head)
  float av_s[4], av_d[4];
#pragma unroll
  for (int n = 0; n < 4; ++n) {
    const int cl = n * 16 + lr;
    av_s[n] = a[wave * 2 * FOUT + cl];
    av_d[n] = a[wave * 2 * FOUT + FOUT + cl];
  }
#pragma unroll
  for (int m = 0; m < 2; ++m)
#pragma unroll
    for (int r = 0; r < 4; ++r) {
      float ps = acc[m][0][r] * av_s[0] + acc[m][1][r] * av_s[1] +
                 acc[m][2][r] * av_s[2] + acc[m][3][r] * av_s[3];
      float pd = acc[m][0][r] * av_d[0] + acc[m][1][r] * av_d[1] +
                 acc[m][2][r] * av_d[2] + acc[m][3][r] * av_d[3];
#pragma unroll
      for (int s = 1; s < 16; s <<= 1) {
        ps += __shfl_xor(ps, s);
        pd += __shfl_xor(pd, s);
      }
      if (lr == 0) {
        const int row = row0 + m * 16 + kq * 4 + r;
        e_src[(size_t)row * HH + wave] = ps;
        e_dst[(size_t)row * HH + wave] = pd;
      }
    }
}

// ---------------------------------------------------------------------------
// K3: fused sparse attention + skip + LayerNorm.
// One WAVE per (b,i) row, 4 rows/block, zero barriers. Natural block order
// (R4's XCD swizzle reverted — unverified mapping, prime regression suspect).
// ---------------------------------------------------------------------------
__global__ __launch_bounds__(256) void k_attn(
    const float* __restrict__ x, const void* __restrict__ adj,
    const int* __restrict__ flag, const unsigned short* __restrict__ Wh,
    const float* __restrict__ e_src, const float* __restrict__ e_dst,
    const float* __restrict__ gamma, const float* __restrict__ beta,
    float* __restrict__ out) {
  __shared__ unsigned short nbrs[4][NN];
  __shared__ float edbuf[4][ECAP * 8];
  __shared__ float esb[4][8], erm[4][8], einv[4][8];

  const int wave = threadIdx.x >> 6, lane = threadIdx.x & 63;
  const int gr = blockIdx.x * 4 + wave;  // global row = b*NN + i
  const int bN = (gr >> 10) << 10;       // b*NN
  const size_t arow = (size_t)gr << 10;
  const int mode = *flag;

  unsigned short* nb = nbrs[wave];
  float* ed = edbuf[wave];

  // ---- phase 1: in-wave neighbor compaction (4 rounds x 4 ballots) ----
  int off = 0;
#pragma unroll
  for (int rr = 0; rr < 4; ++rr) {
    const int j0 = rr * 256 + lane * 4;
    bool v0, v1, v2, v3;
    if (mode == 1) {
      int4 q = *((const int4*)((const int*)adj + arow + j0));
      v0 = q.x != 0; v1 = q.y != 0; v2 = q.z != 0; v3 = q.w != 0;
    } else if (mode == 2) {
      float4 q = *((const float4*)((const float*)adj + arow + j0));
      v0 = q.x != 0.f; v1 = q.y != 0.f; v2 = q.z != 0.f; v3 = q.w != 0.f;
    } else {
      unsigned q = *((const unsigned*)((const unsigned char*)adj + arow + j0));
      v0 = (q & 0xffu) != 0; v1 = (q & 0xff00u) != 0;
      v2 = (q & 0xff0000u) != 0; v3 = (q >> 24) != 0;
    }
    ull m0 = __ballot(v0), m1 = __ballot(v1);
    ull m2 = __ballot(v2), m3 = __ballot(v3);
    const ull below = (1ull << lane) - 1ull;
    int base = off + __popcll(m0 & below) + __popcll(m1 & below) +
               __popcll(m2 & below) + __popcll(m3 & below);
    int c = 0;
    if (v0) nb[base + c++] = (unsigned short)(j0 + 0);
    if (v1) nb[base + c++] = (unsigned short)(j0 + 1);
    if (v2) nb[base + c++] = (unsigned short)(j0 + 2);
    if (v3) nb[base + c++] = (unsigned short)(j0 + 3);
    off += __popcll(m0) + __popcll(m1) + __popcll(m2) + __popcll(m3);
  }
  const int total = off;
  const int ncap = total < ECAP ? total : ECAP;

  // ---- phase 2: gather e_dst (lane=(kq,h)), softmax stats for 8 heads ----
  const int h = lane & 7, kq = lane >> 3;
  for (int k = kq; k < ncap; k += 8)
    ed[k * 8 + h] = e_dst[(size_t)(bN + nb[k]) * HH + h];

  const float es = e_src[(size_t)gr * HH + h];
  float mx = -1e30f;
  for (int k = kq; k < total; k += 8) {
    float v = (k < ECAP) ? ed[k * 8 + h] : e_dst[(size_t)(bN + nb[k]) * HH + h];
    mx = fmaxf(mx, v);
  }
  mx = fmaxf(mx, __shfl_xor(mx, 8));
  mx = fmaxf(mx, __shfl_xor(mx, 16));
  mx = fmaxf(mx, __shfl_xor(mx, 32));
  const float rm = lrelu(es + mx);

  float z = 0.0f;
  for (int k = kq; k < total; k += 8) {
    float v = (k < ECAP) ? ed[k * 8 + h] : e_dst[(size_t)(bN + nb[k]) * HH + h];
    float w = __expf(lrelu(es + v) - rm);
    if (k < ECAP) ed[k * 8 + h] = w;  // unscaled weight
    z += w;
  }
  z += __shfl_xor(z, 8);
  z += __shfl_xor(z, 16);
  z += __shfl_xor(z, 32);
  if (kq == 0) {
    esb[wave][h] = es;
    erm[wave][h] = rm;
    einv[wave][h] = 1.0f / z;
  }

  // ---- phase 3: weighted accumulation, 4-deep pipelined gather ----
  const int h2 = lane >> 3;
  const float es2 = esb[wave][h2], rm2 = erm[wave][h2];
  const int feat = lane * 8;
  const unsigned short* whB = Wh + (size_t)bN * HF + feat;
  float aA0 = 0, aA1 = 0, aA2 = 0, aA3 = 0, aA4 = 0, aA5 = 0, aA6 = 0, aA7 = 0;
  float aB0 = 0, aB1 = 0, aB2 = 0, aB3 = 0, aB4 = 0, aB5 = 0, aB6 = 0, aB7 = 0;
  int k = 0;
  for (; k + 4 <= ncap; k += 4) {
    const unsigned j0 = nb[k + 0], j1 = nb[k + 1];
    const unsigned j2 = nb[k + 2], j3 = nb[k + 3];
    const float w0 = ed[(k + 0) * 8 + h2];
    const float w1 = ed[(k + 1) * 8 + h2];
    const float w2 = ed[(k + 2) * 8 + h2];
    const float w3 = ed[(k + 3) * 8 + h2];
    uint4 q0 = *(const uint4*)(whB + (size_t)j0 * HF);
    uint4 q1 = *(const uint4*)(whB + (size_t)j1 * HF);
    uint4 q2 = *(const uint4*)(whB + (size_t)j2 * HF);
    uint4 q3 = *(const uint4*)(whB + (size_t)j3 * HF);
    aA0 += w0 * bflo(q0.x); aA1 += w0 * bfhi(q0.x);
    aA2 += w0 * bflo(q0.y); aA3 += w0 * bfhi(q0.y);
    aA4 += w0 * bflo(q0.z); aA5 += w0 * bfhi(q0.z);
    aA6 += w0 * bflo(q0.w); aA7 += w0 * bfhi(q0.w);
    aB0 += w1 * bflo(q1.x); aB1 += w1 * bfhi(q1.x);
    aB2 += w1 * bflo(q1.y); aB3 += w1 * bfhi(q1.y);
    aB4 += w1 * bflo(q1.z); aB5 += w1 * bfhi(q1.z);
    aB6 += w1 * bflo(q1.w); aB7 += w1 * bfhi(q1.w);
    aA0 += w2 * bflo(q2.x); aA1 += w2 * bfhi(q2.x);
    aA2 += w2 * bflo(q2.y); aA3 += w2 * bfhi(q2.y);
    aA4 += w2 * bflo(q2.z); aA5 += w2 * bfhi(q2.z);
    aA6 += w2 * bflo(q2.w); aA7 += w2 * bfhi(q2.w);
    aB0 += w3 * bflo(q3.x); aB1 += w3 * bfhi(q3.x);
    aB2 += w3 * bflo(q3.y); aB3 += w3 * bfhi(q3.y);
    aB4 += w3 * bflo(q3.z); aB5 += w3 * bfhi(q3.z);
    aB6 += w3 * bflo(q3.w); aB7 += w3 * bfhi(q3.w);
  }
  for (; k < ncap; ++k) {
    const unsigned j = nb[k];
    const float w = ed[k * 8 + h2];
    uint4 q = *(const uint4*)(whB + (size_t)j * HF);
    aA0 += w * bflo(q.x); aA1 += w * bfhi(q.x);
    aA2 += w * bflo(q.y); aA3 += w * bfhi(q.y);
    aA4 += w * bflo(q.z); aA5 += w * bfhi(q.z);
    aA6 += w * bflo(q.w); aA7 += w * bfhi(q.w);
  }
  for (; k < total; ++k) {  // rare tail beyond ECAP (exact)
    const unsigned j = nb[k];
    const float w = __expf(lrelu(es2 + e_dst[(size_t)(bN + j) * HH + h2]) - rm2);
    uint4 q = *(const uint4*)(whB + (size_t)j * HF);
    aA0 += w * bflo(q.x); aA1 += w * bfhi(q.x);
    aA2 += w * bflo(q.y); aA3 += w * bfhi(q.y);
    aA4 += w * bflo(q.z); aA5 += w * bfhi(q.z);
    aA6 += w * bflo(q.w); aA7 += w * bfhi(q.w);
  }
  const float inv = einv[wave][h2];

  // ---- phase 4: skip + LayerNorm (512 feats across the wave) ----
  const size_t xo = (size_t)gr * HF + feat;
  float4 xv0 = *(const float4*)(x + xo);
  float4 xv1 = *(const float4*)(x + xo + 4);
  float v0 = (aA0 + aB0) * inv + xv0.x, v1 = (aA1 + aB1) * inv + xv0.y;
  float v2 = (aA2 + aB2) * inv + xv0.z, v3 = (aA3 + aB3) * inv + xv0.w;
  float v4 = (aA4 + aB4) * inv + xv1.x, v5 = (aA5 + aB5) * inv + xv1.y;
  float v6 = (aA6 + aB6) * inv + xv1.z, v7 = (aA7 + aB7) * inv + xv1.w;

  float s = v0 + v1 + v2 + v3 + v4 + v5 + v6 + v7;
  float ss = v0 * v0 + v1 * v1 + v2 * v2 + v3 * v3 +
             v4 * v4 + v5 * v5 + v6 * v6 + v7 * v7;
#pragma unroll
  for (int sft = 1; sft < 64; sft <<= 1) {
    s += __shfl_xor(s, sft);
    ss += __shfl_xor(ss, sft);
  }
  const float mu = s * (1.0f / 512.0f);
  const float var = ss * (1.0f / 512.0f) - mu * mu;
  const float rstd = rsqrtf(var + 1e-5f);

  float4 g0 = *(const float4*)(gamma + feat);
  float4 g1 = *(const float4*)(gamma + feat + 4);
  float4 b0 = *(const float4*)(beta + feat);
  float4 b1 = *(const float4*)(beta + feat + 4);
  float4 o0, o1;
  o0.x = (v0 - mu) * rstd * g0.x + b0.x;
  o0.y = (v1 - mu) * rstd * g0.y + b0.y;
  o0.z = (v2 - mu) * rstd * g0.z + b0.z;
  o0.w = (v3 - mu) * rstd * g0.w + b0.w;
  o1.x = (v4 - mu) * rstd * g1.x + b1.x;
  o1.y = (v5 - mu) * rstd * g1.y + b1.y;
  o1.z = (v6 - mu) * rstd * g1.z + b1.z;
  o1.w = (v7 - mu) * rstd * g1.w + b1.w;
  *(float4*)(out + xo) = o0;
  *(float4*)(out + xo + 4) = o1;
}

extern "C" void kernel_launch(void* const* d_in, const int* in_sizes, int n_in,
                              void* d_out, int out_size, void* d_ws,
                              size_t ws_size, hipStream_t stream) {
  const float* x = (const float*)d_in[0];
  const void* adj = d_in[1];
  const float* W = (const float*)d_in[2];
  const float* a = (const float*)d_in[3];
  const float* gamma = (const float*)d_in[4];
  const float* beta = (const float*)d_in[5];
  float* out = (float*)d_out;

  char* ws = (char*)d_ws;
  int* flag = (int*)ws;
  unsigned short* Wh = (unsigned short*)(ws + 256);                // 8 MB
  unsigned short* Wt = (unsigned short*)(ws + 256 + 8388608);      // 512 KB
  float* e_src = (float*)(ws + 256 + 8388608 + 524288);            // 256 KB
  float* e_dst = e_src + (size_t)BB * NN * HH;                     // 256 KB

  k_prep<<<dim3(8, 8), 256, 0, stream>>>(W, Wt, adj, flag);
  k_gemm2<<<256, 512, 0, stream>>>(x, Wt, a, Wh, e_src, e_dst);
  k_attn<<<2048, 256, 0, stream>>>(x, adj, flag, Wh, e_src, e_dst, gamma,
                                   beta, out);
}

// Round 6
// 74.706 us; speedup vs baseline: 1.1314x; 1.0092x over previous
//
#include <hip/hip_runtime.h>
#include <hip/hip_bf16.h>

#define BB 8
#define NN 1024
#define FIN 512
#define HH 8
#define FOUT 64
#define HF 512
#define SLOPE 0.2f
#define ECAP 64

typedef __attribute__((ext_vector_type(8))) short bf16x8;
typedef __attribute__((ext_vector_type(4))) float f32x4;
typedef unsigned long long ull;

static __device__ __forceinline__ float lrelu(float v) { return v > 0.0f ? v : SLOPE * v; }

static __device__ __forceinline__ unsigned short f2bf(float f) {
  __hip_bfloat16 h = __float2bfloat16(f);
  return *reinterpret_cast<unsigned short*>(&h);
}
static __device__ __forceinline__ float bflo(unsigned v) {
  unsigned u = v << 16;
  return *reinterpret_cast<float*>(&u);
}
static __device__ __forceinline__ float bfhi(unsigned v) {
  unsigned u = v & 0xffff0000u;
  return *reinterpret_cast<float*>(&u);
}

// ---------------------------------------------------------------------------
// adjacency dtype detect via guaranteed self-loop diagonal
// mode 1 = int32, mode 2 = float32, mode 0 = 1-byte bool
// ---------------------------------------------------------------------------
static __device__ __forceinline__ void detect_adj(const void* adj, int* flag) {
  const int* ai = (const int*)adj;
  const float* af = (const float*)adj;
  bool oki = true, okf = true;
  for (int i = 0; i < 64; ++i) {
    int d = i * (NN + 1);
    oki = oki && (ai[d] == 1);
    okf = okf && (af[d] == 1.0f);
  }
  *flag = oki ? 1 : (okf ? 2 : 0);
}

// ---------------------------------------------------------------------------
// K1: W transpose+cast: W (FIN x HF, f32) -> Wt (HF x FIN, bf16).
// Block 0 thread 0 also detects adjacency dtype.
// ---------------------------------------------------------------------------
__global__ __launch_bounds__(256) void k_prep(const float* __restrict__ W,
                                              unsigned short* __restrict__ Wt,
                                              const void* __restrict__ adj,
                                              int* __restrict__ flag) {
  if (blockIdx.x == 0 && blockIdx.y == 0 && threadIdx.x == 0)
    detect_adj(adj, flag);
  __shared__ float tile[64][65];
  const int t = threadIdx.x;
  const int r0 = blockIdx.y * 64, c0 = blockIdx.x * 64;
#pragma unroll
  for (int p = 0; p < 16; ++p) {
    int r = (t >> 6) + p * 4;
    tile[t & 63][r] = W[(size_t)(r0 + r) * HF + c0 + (t & 63)];
  }
  __syncthreads();
#pragma unroll
  for (int p = 0; p < 16; ++p) {
    int cc = (t >> 6) + p * 4;
    int rr = t & 63;
    Wt[(size_t)(c0 + cc) * FIN + r0 + rr] = f2bf(tile[cc][rr]);
  }
}

// ---------------------------------------------------------------------------
// K2: Wh = x @ W via bf16 MFMA. Block = 32 rows x 256 cols (4 waves = 4
// heads), grid (256, 2) = 512 blocks = 2 blocks/CU. Double-buffered LDS
// staging with issue-early prefetch (one barrier per k-step). B fragments
// straight from L2-resident Wt. Fused wave-local e_src/e_dst epilogue.
// ---------------------------------------------------------------------------
__global__ __launch_bounds__(256) void k_gemm3(
    const float* __restrict__ x, const unsigned short* __restrict__ Wt,
    const float* __restrict__ a, unsigned short* __restrict__ Wh,
    float* __restrict__ e_src, float* __restrict__ e_dst) {
  __shared__ short As[2][32 * 128];  // 2 x 8 KB, chunk-swizzled

  const int t = threadIdx.x;
  const int wave = t >> 6, lane = t & 63;
  const int row0 = blockIdx.x * 32;
  const int head = blockIdx.y * 4 + wave;
  const int col0 = head * 64;
  const int lr = lane & 15, kq = lane >> 4;

  // staging: thread t stages row = t>>3, chunk pair (t&7)*2 (64 B of f32)
  const int srow = t >> 3;
  const int sc2 = (t & 7) * 2;
  const float* xrow = x + (size_t)(row0 + srow) * FIN + sc2 * 8;
  const int sbyte0 = srow * 128 + ((sc2 + 0) ^ (srow & 7)) * 8;
  const int sbyte1 = srow * 128 + ((sc2 + 1) ^ (srow & 7)) * 8;

  f32x4 acc[2][4] = {};

  // preload step 0
  float4 r0, r1, r2, r3;
  {
    const float4* g = (const float4*)(xrow);
    r0 = g[0]; r1 = g[1]; r2 = g[2]; r3 = g[3];
  }

  int cur = 0;
  for (int step = 0; step < 4; ++step) {
    // write staged regs -> As[cur]
    {
      bf16x8 p0, p1;
      unsigned short* u0 = (unsigned short*)&p0;
      unsigned short* u1 = (unsigned short*)&p1;
      u0[0] = f2bf(r0.x); u0[1] = f2bf(r0.y); u0[2] = f2bf(r0.z); u0[3] = f2bf(r0.w);
      u0[4] = f2bf(r1.x); u0[5] = f2bf(r1.y); u0[6] = f2bf(r1.z); u0[7] = f2bf(r1.w);
      u1[0] = f2bf(r2.x); u1[1] = f2bf(r2.y); u1[2] = f2bf(r2.z); u1[3] = f2bf(r2.w);
      u1[4] = f2bf(r3.x); u1[5] = f2bf(r3.y); u1[6] = f2bf(r3.z); u1[7] = f2bf(r3.w);
      *(bf16x8*)(&As[cur][sbyte0]) = p0;
      *(bf16x8*)(&As[cur][sbyte1]) = p1;
    }
    // issue-early prefetch of next k-tile (consumed after compute)
    if (step < 3) {
      const float4* g = (const float4*)(xrow + (step + 1) * 128);
      r0 = g[0]; r1 = g[1]; r2 = g[2]; r3 = g[3];
    }
    __syncthreads();

    const int k0 = step * 128;
#pragma unroll
    for (int ks = 0; ks < 4; ++ks) {
      bf16x8 af[2];
#pragma unroll
      for (int m = 0; m < 2; ++m) {
        const int row = m * 16 + lr;
        af[m] = *(const bf16x8*)(&As[cur][row * 128 + ((ks * 4 + kq) ^ (row & 7)) * 8]);
      }
#pragma unroll
      for (int n = 0; n < 4; ++n) {
        bf16x8 bfr = *(const bf16x8*)(Wt + (size_t)(col0 + n * 16 + lr) * FIN +
                                      k0 + ks * 32 + kq * 8);
        acc[0][n] = __builtin_amdgcn_mfma_f32_16x16x32_bf16(af[0], bfr, acc[0][n], 0, 0, 0);
        acc[1][n] = __builtin_amdgcn_mfma_f32_16x16x32_bf16(af[1], bfr, acc[1][n], 0, 0, 0);
      }
    }
    cur ^= 1;
  }

  // Wh store (C/D: col=lane&15, row=kq*4+r within frag)
#pragma unroll
  for (int m = 0; m < 2; ++m)
#pragma unroll
    for (int n = 0; n < 4; ++n)
#pragma unroll
      for (int r = 0; r < 4; ++r) {
        const int row = row0 + m * 16 + kq * 4 + r;
        const int col = col0 + n * 16 + lr;
        Wh[(size_t)row * HF + col] = f2bf(acc[m][n][r]);
      }

  // fused e_src/e_dst epilogue (wave owns whole head)
  float av_s[4], av_d[4];
#pragma unroll
  for (int n = 0; n < 4; ++n) {
    const int cl = n * 16 + lr;
    av_s[n] = a[head * 2 * FOUT + cl];
    av_d[n] = a[head * 2 * FOUT + FOUT + cl];
  }
#pragma unroll
  for (int m = 0; m < 2; ++m)
#pragma unroll
    for (int r = 0; r < 4; ++r) {
      float ps = acc[m][0][r] * av_s[0] + acc[m][1][r] * av_s[1] +
                 acc[m][2][r] * av_s[2] + acc[m][3][r] * av_s[3];
      float pd = acc[m][0][r] * av_d[0] + acc[m][1][r] * av_d[1] +
                 acc[m][2][r] * av_d[2] + acc[m][3][r] * av_d[3];
#pragma unroll
      for (int s = 1; s < 16; s <<= 1) {
        ps += __shfl_xor(ps, s);
        pd += __shfl_xor(pd, s);
      }
      if (lr == 0) {
        const int row = row0 + m * 16 + kq * 4 + r;
        e_src[(size_t)row * HH + head] = ps;
        e_dst[(size_t)row * HH + head] = pd;
      }
    }
}

// ---------------------------------------------------------------------------
// K3: fused sparse attention + skip + LayerNorm. (byte-identical to R5)
// One WAVE per (b,i) row, 4 rows/block, zero barriers.
// ---------------------------------------------------------------------------
__global__ __launch_bounds__(256) void k_attn(
    const float* __restrict__ x, const void* __restrict__ adj,
    const int* __restrict__ flag, const unsigned short* __restrict__ Wh,
    const float* __restrict__ e_src, const float* __restrict__ e_dst,
    const float* __restrict__ gamma, const float* __restrict__ beta,
    float* __restrict__ out) {
  __shared__ unsigned short nbrs[4][NN];
  __shared__ float edbuf[4][ECAP * 8];
  __shared__ float esb[4][8], erm[4][8], einv[4][8];

  const int wave = threadIdx.x >> 6, lane = threadIdx.x & 63;
  const int gr = blockIdx.x * 4 + wave;  // global row = b*NN + i
  const int bN = (gr >> 10) << 10;       // b*NN
  const size_t arow = (size_t)gr << 10;
  const int mode = *flag;

  unsigned short* nb = nbrs[wave];
  float* ed = edbuf[wave];

  // ---- phase 1: in-wave neighbor compaction (4 rounds x 4 ballots) ----
  int off = 0;
#pragma unroll
  for (int rr = 0; rr < 4; ++rr) {
    const int j0 = rr * 256 + lane * 4;
    bool v0, v1, v2, v3;
    if (mode == 1) {
      int4 q = *((const int4*)((const int*)adj + arow + j0));
      v0 = q.x != 0; v1 = q.y != 0; v2 = q.z != 0; v3 = q.w != 0;
    } else if (mode == 2) {
      float4 q = *((const float4*)((const float*)adj + arow + j0));
      v0 = q.x != 0.f; v1 = q.y != 0.f; v2 = q.z != 0.f; v3 = q.w != 0.f;
    } else {
      unsigned q = *((const unsigned*)((const unsigned char*)adj + arow + j0));
      v0 = (q & 0xffu) != 0; v1 = (q & 0xff00u) != 0;
      v2 = (q & 0xff0000u) != 0; v3 = (q >> 24) != 0;
    }
    ull m0 = __ballot(v0), m1 = __ballot(v1);
    ull m2 = __ballot(v2), m3 = __ballot(v3);
    const ull below = (1ull << lane) - 1ull;
    int base = off + __popcll(m0 & below) + __popcll(m1 & below) +
               __popcll(m2 & below) + __popcll(m3 & below);
    int c = 0;
    if (v0) nb[base + c++] = (unsigned short)(j0 + 0);
    if (v1) nb[base + c++] = (unsigned short)(j0 + 1);
    if (v2) nb[base + c++] = (unsigned short)(j0 + 2);
    if (v3) nb[base + c++] = (unsigned short)(j0 + 3);
    off += __popcll(m0) + __popcll(m1) + __popcll(m2) + __popcll(m3);
  }
  const int total = off;
  const int ncap = total < ECAP ? total : ECAP;

  // ---- phase 2: gather e_dst (lane=(kq,h)), softmax stats for 8 heads ----
  const int h = lane & 7, kq = lane >> 3;
  for (int k = kq; k < ncap; k += 8)
    ed[k * 8 + h] = e_dst[(size_t)(bN + nb[k]) * HH + h];

  const float es = e_src[(size_t)gr * HH + h];
  float mx = -1e30f;
  for (int k = kq; k < total; k += 8) {
    float v = (k < ECAP) ? ed[k * 8 + h] : e_dst[(size_t)(bN + nb[k]) * HH + h];
    mx = fmaxf(mx, v);
  }
  mx = fmaxf(mx, __shfl_xor(mx, 8));
  mx = fmaxf(mx, __shfl_xor(mx, 16));
  mx = fmaxf(mx, __shfl_xor(mx, 32));
  const float rm = lrelu(es + mx);

  float z = 0.0f;
  for (int k = kq; k < total; k += 8) {
    float v = (k < ECAP) ? ed[k * 8 + h] : e_dst[(size_t)(bN + nb[k]) * HH + h];
    float w = __expf(lrelu(es + v) - rm);
    if (k < ECAP) ed[k * 8 + h] = w;  // unscaled weight
    z += w;
  }
  z += __shfl_xor(z, 8);
  z += __shfl_xor(z, 16);
  z += __shfl_xor(z, 32);
  if (kq == 0) {
    esb[wave][h] = es;
    erm[wave][h] = rm;
    einv[wave][h] = 1.0f / z;
  }

  // ---- phase 3: weighted accumulation, 4-deep pipelined gather ----
  const int h2 = lane >> 3;
  const float es2 = esb[wave][h2], rm2 = erm[wave][h2];
  const int feat = lane * 8;
  const unsigned short* whB = Wh + (size_t)bN * HF + feat;
  float aA0 = 0, aA1 = 0, aA2 = 0, aA3 = 0, aA4 = 0, aA5 = 0, aA6 = 0, aA7 = 0;
  float aB0 = 0, aB1 = 0, aB2 = 0, aB3 = 0, aB4 = 0, aB5 = 0, aB6 = 0, aB7 = 0;
  int k = 0;
  for (; k + 4 <= ncap; k += 4) {
    const unsigned j0 = nb[k + 0], j1 = nb[k + 1];
    const unsigned j2 = nb[k + 2], j3 = nb[k + 3];
    const float w0 = ed[(k + 0) * 8 + h2];
    const float w1 = ed[(k + 1) * 8 + h2];
    const float w2 = ed[(k + 2) * 8 + h2];
    const float w3 = ed[(k + 3) * 8 + h2];
    uint4 q0 = *(const uint4*)(whB + (size_t)j0 * HF);
    uint4 q1 = *(const uint4*)(whB + (size_t)j1 * HF);
    uint4 q2 = *(const uint4*)(whB + (size_t)j2 * HF);
    uint4 q3 = *(const uint4*)(whB + (size_t)j3 * HF);
    aA0 += w0 * bflo(q0.x); aA1 += w0 * bfhi(q0.x);
    aA2 += w0 * bflo(q0.y); aA3 += w0 * bfhi(q0.y);
    aA4 += w0 * bflo(q0.z); aA5 += w0 * bfhi(q0.z);
    aA6 += w0 * bflo(q0.w); aA7 += w0 * bfhi(q0.w);
    aB0 += w1 * bflo(q1.x); aB1 += w1 * bfhi(q1.x);
    aB2 += w1 * bflo(q1.y); aB3 += w1 * bfhi(q1.y);
    aB4 += w1 * bflo(q1.z); aB5 += w1 * bfhi(q1.z);
    aB6 += w1 * bflo(q1.w); aB7 += w1 * bfhi(q1.w);
    aA0 += w2 * bflo(q2.x); aA1 += w2 * bfhi(q2.x);
    aA2 += w2 * bflo(q2.y); aA3 += w2 * bfhi(q2.y);
    aA4 += w2 * bflo(q2.z); aA5 += w2 * bfhi(q2.z);
    aA6 += w2 * bflo(q2.w); aA7 += w2 * bfhi(q2.w);
    aB0 += w3 * bflo(q3.x); aB1 += w3 * bfhi(q3.x);
    aB2 += w3 * bflo(q3.y); aB3 += w3 * bfhi(q3.y);
    aB4 += w3 * bflo(q3.z); aB5 += w3 * bfhi(q3.z);
    aB6 += w3 * bflo(q3.w); aB7 += w3 * bfhi(q3.w);
  }
  for (; k < ncap; ++k) {
    const unsigned j = nb[k];
    const float w = ed[k * 8 + h2];
    uint4 q = *(const uint4*)(whB + (size_t)j * HF);
    aA0 += w * bflo(q.x); aA1 += w * bfhi(q.x);
    aA2 += w * bflo(q.y); aA3 += w * bfhi(q.y);
    aA4 += w * bflo(q.z); aA5 += w * bfhi(q.z);
    aA6 += w * bflo(q.w); aA7 += w * bfhi(q.w);
  }
  for (; k < total; ++k) {  // rare tail beyond ECAP (exact)
    const unsigned j = nb[k];
    const float w = __expf(lrelu(es2 + e_dst[(size_t)(bN + j) * HH + h2]) - rm2);
    uint4 q = *(const uint4*)(whB + (size_t)j * HF);
    aA0 += w * bflo(q.x); aA1 += w * bfhi(q.x);
    aA2 += w * bflo(q.y); aA3 += w * bfhi(q.y);
    aA4 += w * bflo(q.z); aA5 += w * bfhi(q.z);
    aA6 += w * bflo(q.w); aA7 += w * bfhi(q.w);
  }
  const float inv = einv[wave][h2];

  // ---- phase 4: skip + LayerNorm (512 feats across the wave) ----
  const size_t xo = (size_t)gr * HF + feat;
  float4 xv0 = *(const float4*)(x + xo);
  float4 xv1 = *(const float4*)(x + xo + 4);
  float v0 = (aA0 + aB0) * inv + xv0.x, v1 = (aA1 + aB1) * inv + xv0.y;
  float v2 = (aA2 + aB2) * inv + xv0.z, v3 = (aA3 + aB3) * inv + xv0.w;
  float v4 = (aA4 + aB4) * inv + xv1.x, v5 = (aA5 + aB5) * inv + xv1.y;
  float v6 = (aA6 + aB6) * inv + xv1.z, v7 = (aA7 + aB7) * inv + xv1.w;

  float s = v0 + v1 + v2 + v3 + v4 + v5 + v6 + v7;
  float ss = v0 * v0 + v1 * v1 + v2 * v2 + v3 * v3 +
             v4 * v4 + v5 * v5 + v6 * v6 + v7 * v7;
#pragma unroll
  for (int sft = 1; sft < 64; sft <<= 1) {
    s += __shfl_xor(s, sft);
    ss += __shfl_xor(ss, sft);
  }
  const float mu = s * (1.0f / 512.0f);
  const float var = ss * (1.0f / 512.0f) - mu * mu;
  const float rstd = rsqrtf(var + 1e-5f);

  float4 g0 = *(const float4*)(gamma + feat);
  float4 g1 = *(const float4*)(gamma + feat + 4);
  float4 b0 = *(const float4*)(beta + feat);
  float4 b1 = *(const float4*)(beta + feat + 4);
  float4 o0, o1;
  o0.x = (v0 - mu) * rstd * g0.x + b0.x;
  o0.y = (v1 - mu) * rstd * g0.y + b0.y;
  o0.z = (v2 - mu) * rstd * g0.z + b0.z;
  o0.w = (v3 - mu) * rstd * g0.w + b0.w;
  o1.x = (v4 - mu) * rstd * g1.x + b1.x;
  o1.y = (v5 - mu) * rstd * g1.y + b1.y;
  o1.z = (v6 - mu) * rstd * g1.z + b1.z;
  o1.w = (v7 - mu) * rstd * g1.w + b1.w;
  *(float4*)(out + xo) = o0;
  *(float4*)(out + xo + 4) = o1;
}

extern "C" void kernel_launch(void* const* d_in, const int* in_sizes, int n_in,
                              void* d_out, int out_size, void* d_ws,
                              size_t ws_size, hipStream_t stream) {
  const float* x = (const float*)d_in[0];
  const void* adj = d_in[1];
  const float* W = (const float*)d_in[2];
  const float* a = (const float*)d_in[3];
  const float* gamma = (const float*)d_in[4];
  const float* beta = (const float*)d_in[5];
  float* out = (float*)d_out;

  char* ws = (char*)d_ws;
  int* flag = (int*)ws;
  unsigned short* Wh = (unsigned short*)(ws + 256);                // 8 MB
  unsigned short* Wt = (unsigned short*)(ws + 256 + 8388608);      // 512 KB
  float* e_src = (float*)(ws + 256 + 8388608 + 524288);            // 256 KB
  float* e_dst = e_src + (size_t)BB * NN * HH;                     // 256 KB

  k_prep<<<dim3(8, 8), 256, 0, stream>>>(W, Wt, adj, flag);
  k_gemm3<<<dim3(256, 2), 256, 0, stream>>>(x, Wt, a, Wh, e_src, e_dst);
  k_attn<<<2048, 256, 0, stream>>>(x, adj, flag, Wh, e_src, e_dst, gamma,
                                   beta, out);
}

// Round 7
// 71.403 us; speedup vs baseline: 1.1837x; 1.0463x over previous
//
#include <hip/hip_runtime.h>
#include <hip/hip_bf16.h>

#define BB 8
#define NN 1024
#define FIN 512
#define HH 8
#define FOUT 64
#define HF 512
#define SLOPE 0.2f
#define ECAP 64

typedef __attribute__((ext_vector_type(8))) short bf16x8;
typedef __attribute__((ext_vector_type(4))) float f32x4;
typedef unsigned long long ull;

static __device__ __forceinline__ float lrelu(float v) { return v > 0.0f ? v : SLOPE * v; }

static __device__ __forceinline__ unsigned short f2bf(float f) {
  __hip_bfloat16 h = __float2bfloat16(f);
  return *reinterpret_cast<unsigned short*>(&h);
}
static __device__ __forceinline__ float bflo(unsigned v) {
  unsigned u = v << 16;
  return *reinterpret_cast<float*>(&u);
}
static __device__ __forceinline__ float bfhi(unsigned v) {
  unsigned u = v & 0xffff0000u;
  return *reinterpret_cast<float*>(&u);
}

// ---------------------------------------------------------------------------
// adjacency dtype detect via guaranteed self-loop diagonal
// mode 1 = int32, mode 2 = float32, mode 0 = 1-byte bool
// ---------------------------------------------------------------------------
static __device__ __forceinline__ void detect_adj(const void* adj, int* flag) {
  const int* ai = (const int*)adj;
  const float* af = (const float*)adj;
  bool oki = true, okf = true;
  for (int i = 0; i < 64; ++i) {
    int d = i * (NN + 1);
    oki = oki && (ai[d] == 1);
    okf = okf && (af[d] == 1.0f);
  }
  *flag = oki ? 1 : (okf ? 2 : 0);
}

// ---------------------------------------------------------------------------
// K1: W transpose+cast: W (FIN x HF, f32) -> Wt (HF x FIN, bf16).
// Block 0 thread 0 also detects adjacency dtype.
// ---------------------------------------------------------------------------
__global__ __launch_bounds__(256) void k_prep(const float* __restrict__ W,
                                              unsigned short* __restrict__ Wt,
                                              const void* __restrict__ adj,
                                              int* __restrict__ flag) {
  if (blockIdx.x == 0 && blockIdx.y == 0 && threadIdx.x == 0)
    detect_adj(adj, flag);
  __shared__ float tile[64][65];
  const int t = threadIdx.x;
  const int r0 = blockIdx.y * 64, c0 = blockIdx.x * 64;
#pragma unroll
  for (int p = 0; p < 16; ++p) {
    int r = (t >> 6) + p * 4;
    tile[t & 63][r] = W[(size_t)(r0 + r) * HF + c0 + (t & 63)];
  }
  __syncthreads();
#pragma unroll
  for (int p = 0; p < 16; ++p) {
    int cc = (t >> 6) + p * 4;
    int rr = t & 63;
    Wt[(size_t)(c0 + cc) * FIN + r0 + rr] = f2bf(tile[cc][rr]);
  }
}

// ---------------------------------------------------------------------------
// K2: Wh = x @ W via bf16 MFMA. Block = 32 rows x 256 cols (4 waves = 4
// heads), grid (256, 2) = 512 blocks = 2 blocks/CU. Double-buffered LDS
// staging with issue-early prefetch (one barrier per k-step). B fragments
// straight from L2-resident Wt. Fused wave-local e_src/e_dst epilogue.
// (byte-identical to R6)
// ---------------------------------------------------------------------------
__global__ __launch_bounds__(256) void k_gemm3(
    const float* __restrict__ x, const unsigned short* __restrict__ Wt,
    const float* __restrict__ a, unsigned short* __restrict__ Wh,
    float* __restrict__ e_src, float* __restrict__ e_dst) {
  __shared__ short As[2][32 * 128];  // 2 x 8 KB, chunk-swizzled

  const int t = threadIdx.x;
  const int wave = t >> 6, lane = t & 63;
  const int row0 = blockIdx.x * 32;
  const int head = blockIdx.y * 4 + wave;
  const int col0 = head * 64;
  const int lr = lane & 15, kq = lane >> 4;

  // staging: thread t stages row = t>>3, chunk pair (t&7)*2 (64 B of f32)
  const int srow = t >> 3;
  const int sc2 = (t & 7) * 2;
  const float* xrow = x + (size_t)(row0 + srow) * FIN + sc2 * 8;
  const int sbyte0 = srow * 128 + ((sc2 + 0) ^ (srow & 7)) * 8;
  const int sbyte1 = srow * 128 + ((sc2 + 1) ^ (srow & 7)) * 8;

  f32x4 acc[2][4] = {};

  // preload step 0
  float4 r0, r1, r2, r3;
  {
    const float4* g = (const float4*)(xrow);
    r0 = g[0]; r1 = g[1]; r2 = g[2]; r3 = g[3];
  }

  int cur = 0;
  for (int step = 0; step < 4; ++step) {
    // write staged regs -> As[cur]
    {
      bf16x8 p0, p1;
      unsigned short* u0 = (unsigned short*)&p0;
      unsigned short* u1 = (unsigned short*)&p1;
      u0[0] = f2bf(r0.x); u0[1] = f2bf(r0.y); u0[2] = f2bf(r0.z); u0[3] = f2bf(r0.w);
      u0[4] = f2bf(r1.x); u0[5] = f2bf(r1.y); u0[6] = f2bf(r1.z); u0[7] = f2bf(r1.w);
      u1[0] = f2bf(r2.x); u1[1] = f2bf(r2.y); u1[2] = f2bf(r2.z); u1[3] = f2bf(r2.w);
      u1[4] = f2bf(r3.x); u1[5] = f2bf(r3.y); u1[6] = f2bf(r3.z); u1[7] = f2bf(r3.w);
      *(bf16x8*)(&As[cur][sbyte0]) = p0;
      *(bf16x8*)(&As[cur][sbyte1]) = p1;
    }
    // issue-early prefetch of next k-tile (consumed after compute)
    if (step < 3) {
      const float4* g = (const float4*)(xrow + (step + 1) * 128);
      r0 = g[0]; r1 = g[1]; r2 = g[2]; r3 = g[3];
    }
    __syncthreads();

    const int k0 = step * 128;
#pragma unroll
    for (int ks = 0; ks < 4; ++ks) {
      bf16x8 af[2];
#pragma unroll
      for (int m = 0; m < 2; ++m) {
        const int row = m * 16 + lr;
        af[m] = *(const bf16x8*)(&As[cur][row * 128 + ((ks * 4 + kq) ^ (row & 7)) * 8]);
      }
#pragma unroll
      for (int n = 0; n < 4; ++n) {
        bf16x8 bfr = *(const bf16x8*)(Wt + (size_t)(col0 + n * 16 + lr) * FIN +
                                      k0 + ks * 32 + kq * 8);
        acc[0][n] = __builtin_amdgcn_mfma_f32_16x16x32_bf16(af[0], bfr, acc[0][n], 0, 0, 0);
        acc[1][n] = __builtin_amdgcn_mfma_f32_16x16x32_bf16(af[1], bfr, acc[1][n], 0, 0, 0);
      }
    }
    cur ^= 1;
  }

  // Wh store (C/D: col=lane&15, row=kq*4+r within frag)
#pragma unroll
  for (int m = 0; m < 2; ++m)
#pragma unroll
    for (int n = 0; n < 4; ++n)
#pragma unroll
      for (int r = 0; r < 4; ++r) {
        const int row = row0 + m * 16 + kq * 4 + r;
        const int col = col0 + n * 16 + lr;
        Wh[(size_t)row * HF + col] = f2bf(acc[m][n][r]);
      }

  // fused e_src/e_dst epilogue (wave owns whole head)
  float av_s[4], av_d[4];
#pragma unroll
  for (int n = 0; n < 4; ++n) {
    const int cl = n * 16 + lr;
    av_s[n] = a[head * 2 * FOUT + cl];
    av_d[n] = a[head * 2 * FOUT + FOUT + cl];
  }
#pragma unroll
  for (int m = 0; m < 2; ++m)
#pragma unroll
    for (int r = 0; r < 4; ++r) {
      float ps = acc[m][0][r] * av_s[0] + acc[m][1][r] * av_s[1] +
                 acc[m][2][r] * av_s[2] + acc[m][3][r] * av_s[3];
      float pd = acc[m][0][r] * av_d[0] + acc[m][1][r] * av_d[1] +
                 acc[m][2][r] * av_d[2] + acc[m][3][r] * av_d[3];
#pragma unroll
      for (int s = 1; s < 16; s <<= 1) {
        ps += __shfl_xor(ps, s);
        pd += __shfl_xor(pd, s);
      }
      if (lr == 0) {
        const int row = row0 + m * 16 + kq * 4 + r;
        e_src[(size_t)row * HH + head] = ps;
        e_dst[(size_t)row * HH + head] = pd;
      }
    }
}

// ---------------------------------------------------------------------------
// K3: fused sparse attention + skip + LayerNorm.
// One WAVE per (b,i) row, 4 rows/block, zero barriers.
// ONLY change vs R6: batch-aligned XCD swizzle. Blocks with bid%8==x handle
// batch x exclusively (2048%8==0, bijective) -> XCD x's L2 holds batch x's
// 1 MB Wh slice + 32 KB e_dst for all its gathers.
// ---------------------------------------------------------------------------
__global__ __launch_bounds__(256) void k_attn(
    const float* __restrict__ x, const void* __restrict__ adj,
    const int* __restrict__ flag, const unsigned short* __restrict__ Wh,
    const float* __restrict__ e_src, const float* __restrict__ e_dst,
    const float* __restrict__ gamma, const float* __restrict__ beta,
    float* __restrict__ out) {
  __shared__ unsigned short nbrs[4][NN];
  __shared__ float edbuf[4][ECAP * 8];
  __shared__ float esb[4][8], erm[4][8], einv[4][8];

  const int wave = threadIdx.x >> 6, lane = threadIdx.x & 63;
  const int bid = blockIdx.x;
  const int nbid = (bid & 7) * 256 + (bid >> 3);  // XCD-batch alignment
  const int gr = nbid * 4 + wave;        // global row = b*NN + i
  const int bN = (gr >> 10) << 10;       // b*NN
  const size_t arow = (size_t)gr << 10;
  const int mode = *flag;

  unsigned short* nb = nbrs[wave];
  float* ed = edbuf[wave];

  // ---- phase 1: in-wave neighbor compaction (4 rounds x 4 ballots) ----
  int off = 0;
#pragma unroll
  for (int rr = 0; rr < 4; ++rr) {
    const int j0 = rr * 256 + lane * 4;
    bool v0, v1, v2, v3;
    if (mode == 1) {
      int4 q = *((const int4*)((const int*)adj + arow + j0));
      v0 = q.x != 0; v1 = q.y != 0; v2 = q.z != 0; v3 = q.w != 0;
    } else if (mode == 2) {
      float4 q = *((const float4*)((const float*)adj + arow + j0));
      v0 = q.x != 0.f; v1 = q.y != 0.f; v2 = q.z != 0.f; v3 = q.w != 0.f;
    } else {
      unsigned q = *((const unsigned*)((const unsigned char*)adj + arow + j0));
      v0 = (q & 0xffu) != 0; v1 = (q & 0xff00u) != 0;
      v2 = (q & 0xff0000u) != 0; v3 = (q >> 24) != 0;
    }
    ull m0 = __ballot(v0), m1 = __ballot(v1);
    ull m2 = __ballot(v2), m3 = __ballot(v3);
    const ull below = (1ull << lane) - 1ull;
    int base = off + __popcll(m0 & below) + __popcll(m1 & below) +
               __popcll(m2 & below) + __popcll(m3 & below);
    int c = 0;
    if (v0) nb[base + c++] = (unsigned short)(j0 + 0);
    if (v1) nb[base + c++] = (unsigned short)(j0 + 1);
    if (v2) nb[base + c++] = (unsigned short)(j0 + 2);
    if (v3) nb[base + c++] = (unsigned short)(j0 + 3);
    off += __popcll(m0) + __popcll(m1) + __popcll(m2) + __popcll(m3);
  }
  const int total = off;
  const int ncap = total < ECAP ? total : ECAP;

  // ---- phase 2: gather e_dst (lane=(kq,h)), softmax stats for 8 heads ----
  const int h = lane & 7, kq = lane >> 3;
  for (int k = kq; k < ncap; k += 8)
    ed[k * 8 + h] = e_dst[(size_t)(bN + nb[k]) * HH + h];

  const float es = e_src[(size_t)gr * HH + h];
  float mx = -1e30f;
  for (int k = kq; k < total; k += 8) {
    float v = (k < ECAP) ? ed[k * 8 + h] : e_dst[(size_t)(bN + nb[k]) * HH + h];
    mx = fmaxf(mx, v);
  }
  mx = fmaxf(mx, __shfl_xor(mx, 8));
  mx = fmaxf(mx, __shfl_xor(mx, 16));
  mx = fmaxf(mx, __shfl_xor(mx, 32));
  const float rm = lrelu(es + mx);

  float z = 0.0f;
  for (int k = kq; k < total; k += 8) {
    float v = (k < ECAP) ? ed[k * 8 + h] : e_dst[(size_t)(bN + nb[k]) * HH + h];
    float w = __expf(lrelu(es + v) - rm);
    if (k < ECAP) ed[k * 8 + h] = w;  // unscaled weight
    z += w;
  }
  z += __shfl_xor(z, 8);
  z += __shfl_xor(z, 16);
  z += __shfl_xor(z, 32);
  if (kq == 0) {
    esb[wave][h] = es;
    erm[wave][h] = rm;
    einv[wave][h] = 1.0f / z;
  }

  // ---- phase 3: weighted accumulation, 4-deep pipelined gather ----
  const int h2 = lane >> 3;
  const float es2 = esb[wave][h2], rm2 = erm[wave][h2];
  const int feat = lane * 8;
  const unsigned short* whB = Wh + (size_t)bN * HF + feat;
  float aA0 = 0, aA1 = 0, aA2 = 0, aA3 = 0, aA4 = 0, aA5 = 0, aA6 = 0, aA7 = 0;
  float aB0 = 0, aB1 = 0, aB2 = 0, aB3 = 0, aB4 = 0, aB5 = 0, aB6 = 0, aB7 = 0;
  int k = 0;
  for (; k + 4 <= ncap; k += 4) {
    const unsigned j0 = nb[k + 0], j1 = nb[k + 1];
    const unsigned j2 = nb[k + 2], j3 = nb[k + 3];
    const float w0 = ed[(k + 0) * 8 + h2];
    const float w1 = ed[(k + 1) * 8 + h2];
    const float w2 = ed[(k + 2) * 8 + h2];
    const float w3 = ed[(k + 3) * 8 + h2];
    uint4 q0 = *(const uint4*)(whB + (size_t)j0 * HF);
    uint4 q1 = *(const uint4*)(whB + (size_t)j1 * HF);
    uint4 q2 = *(const uint4*)(whB + (size_t)j2 * HF);
    uint4 q3 = *(const uint4*)(whB + (size_t)j3 * HF);
    aA0 += w0 * bflo(q0.x); aA1 += w0 * bfhi(q0.x);
    aA2 += w0 * bflo(q0.y); aA3 += w0 * bfhi(q0.y);
    aA4 += w0 * bflo(q0.z); aA5 += w0 * bfhi(q0.z);
    aA6 += w0 * bflo(q0.w); aA7 += w0 * bfhi(q0.w);
    aB0 += w1 * bflo(q1.x); aB1 += w1 * bfhi(q1.x);
    aB2 += w1 * bflo(q1.y); aB3 += w1 * bfhi(q1.y);
    aB4 += w1 * bflo(q1.z); aB5 += w1 * bfhi(q1.z);
    aB6 += w1 * bflo(q1.w); aB7 += w1 * bfhi(q1.w);
    aA0 += w2 * bflo(q2.x); aA1 += w2 * bfhi(q2.x);
    aA2 += w2 * bflo(q2.y); aA3 += w2 * bfhi(q2.y);
    aA4 += w2 * bflo(q2.z); aA5 += w2 * bfhi(q2.z);
    aA6 += w2 * bflo(q2.w); aA7 += w2 * bfhi(q2.w);
    aB0 += w3 * bflo(q3.x); aB1 += w3 * bfhi(q3.x);
    aB2 += w3 * bflo(q3.y); aB3 += w3 * bfhi(q3.y);
    aB4 += w3 * bflo(q3.z); aB5 += w3 * bfhi(q3.z);
    aB6 += w3 * bflo(q3.w); aB7 += w3 * bfhi(q3.w);
  }
  for (; k < ncap; ++k) {
    const unsigned j = nb[k];
    const float w = ed[k * 8 + h2];
    uint4 q = *(const uint4*)(whB + (size_t)j * HF);
    aA0 += w * bflo(q.x); aA1 += w * bfhi(q.x);
    aA2 += w * bflo(q.y); aA3 += w * bfhi(q.y);
    aA4 += w * bflo(q.z); aA5 += w * bfhi(q.z);
    aA6 += w * bflo(q.w); aA7 += w * bfhi(q.w);
  }
  for (; k < total; ++k) {  // rare tail beyond ECAP (exact)
    const unsigned j = nb[k];
    const float w = __expf(lrelu(es2 + e_dst[(size_t)(bN + j) * HH + h2]) - rm2);
    uint4 q = *(const uint4*)(whB + (size_t)j * HF);
    aA0 += w * bflo(q.x); aA1 += w * bfhi(q.x);
    aA2 += w * bflo(q.y); aA3 += w * bfhi(q.y);
    aA4 += w * bflo(q.z); aA5 += w * bfhi(q.z);
    aA6 += w * bflo(q.w); aA7 += w * bfhi(q.w);
  }
  const float inv = einv[wave][h2];

  // ---- phase 4: skip + LayerNorm (512 feats across the wave) ----
  const size_t xo = (size_t)gr * HF + feat;
  float4 xv0 = *(const float4*)(x + xo);
  float4 xv1 = *(const float4*)(x + xo + 4);
  float v0 = (aA0 + aB0) * inv + xv0.x, v1 = (aA1 + aB1) * inv + xv0.y;
  float v2 = (aA2 + aB2) * inv + xv0.z, v3 = (aA3 + aB3) * inv + xv0.w;
  float v4 = (aA4 + aB4) * inv + xv1.x, v5 = (aA5 + aB5) * inv + xv1.y;
  float v6 = (aA6 + aB6) * inv + xv1.z, v7 = (aA7 + aB7) * inv + xv1.w;

  float s = v0 + v1 + v2 + v3 + v4 + v5 + v6 + v7;
  float ss = v0 * v0 + v1 * v1 + v2 * v2 + v3 * v3 +
             v4 * v4 + v5 * v5 + v6 * v6 + v7 * v7;
#pragma unroll
  for (int sft = 1; sft < 64; sft <<= 1) {
    s += __shfl_xor(s, sft);
    ss += __shfl_xor(ss, sft);
  }
  const float mu = s * (1.0f / 512.0f);
  const float var = ss * (1.0f / 512.0f) - mu * mu;
  const float rstd = rsqrtf(var + 1e-5f);

  float4 g0 = *(const float4*)(gamma + feat);
  float4 g1 = *(const float4*)(gamma + feat + 4);
  float4 b0 = *(const float4*)(beta + feat);
  float4 b1 = *(const float4*)(beta + feat + 4);
  float4 o0, o1;
  o0.x = (v0 - mu) * rstd * g0.x + b0.x;
  o0.y = (v1 - mu) * rstd * g0.y + b0.y;
  o0.z = (v2 - mu) * rstd * g0.z + b0.z;
  o0.w = (v3 - mu) * rstd * g0.w + b0.w;
  o1.x = (v4 - mu) * rstd * g1.x + b1.x;
  o1.y = (v5 - mu) * rstd * g1.y + b1.y;
  o1.z = (v6 - mu) * rstd * g1.z + b1.z;
  o1.w = (v7 - mu) * rstd * g1.w + b1.w;
  *(float4*)(out + xo) = o0;
  *(float4*)(out + xo + 4) = o1;
}

extern "C" void kernel_launch(void* const* d_in, const int* in_sizes, int n_in,
                              void* d_out, int out_size, void* d_ws,
                              size_t ws_size, hipStream_t stream) {
  const float* x = (const float*)d_in[0];
  const void* adj = d_in[1];
  const float* W = (const float*)d_in[2];
  const float* a = (const float*)d_in[3];
  const float* gamma = (const float*)d_in[4];
  const float* beta = (const float*)d_in[5];
  float* out = (float*)d_out;

  char* ws = (char*)d_ws;
  int* flag = (int*)ws;
  unsigned short* Wh = (unsigned short*)(ws + 256);                // 8 MB
  unsigned short* Wt = (unsigned short*)(ws + 256 + 8388608);      // 512 KB
  float* e_src = (float*)(ws + 256 + 8388608 + 524288);            // 256 KB
  float* e_dst = e_src + (size_t)BB * NN * HH;                     // 256 KB

  k_prep<<<dim3(8, 8), 256, 0, stream>>>(W, Wt, adj, flag);
  k_gemm3<<<dim3(256, 2), 256, 0, stream>>>(x, Wt, a, Wh, e_src, e_dst);
  k_attn<<<2048, 256, 0, stream>>>(x, adj, flag, Wh, e_src, e_dst, gamma,
                                   beta, out);
}